// Round 3
// baseline (487.447 us; speedup 1.0000x reference)
//
#include <hip/hip_runtime.h>

#define E_CNT 500000
#define N_CNT 100000
#define HID   256
#define NTILE 31250   // E/16

typedef short short8 __attribute__((ext_vector_type(8)));
typedef short short4v __attribute__((ext_vector_type(4)));
typedef float f32x4 __attribute__((ext_vector_type(4)));

__device__ __forceinline__ unsigned short f2bf(float f){
  union { float f; unsigned int i; } v; v.f = f;
  unsigned int u = v.i;
  u = u + 0x7FFFu + ((u >> 16) & 1u);
  return (unsigned short)(u >> 16);
}

// Build the 16 A-fragments of W1-augmented (K=32: k0..7=W1, k8..15=W1 again,
// k16=2*b1, rest 0).  mfma_f32_16x16x32_bf16 A layout: m=lane&15, k=(lane>>4)*8+j.
// W1, b1 are fp32 here; converted to bf16 on load.
__device__ __forceinline__ void build_w1_frags(const float* W1, const float* b1,
                                               short8* fr, int lane){
  int m = lane & 15, q = lane >> 4;
  #pragma unroll
  for (int nt = 0; nt < 16; ++nt){
    int col = nt * 16 + m;
    short8 a = {0,0,0,0,0,0,0,0};
    if (q < 2){
      #pragma unroll
      for (int j = 0; j < 8; ++j) a[j] = (short)f2bf(W1[j * HID + col]);
    } else if (q == 2){
      a[0] = (short)f2bf(2.0f * b1[col]);
    }
    fr[nt] = a;
  }
}

// ---------- weight chain, scalar fp32, one thread per output element --------
__global__ void kc1(const float* __restrict__ Wo, const float* __restrict__ Wp,
                    float* __restrict__ T1){
  int t = blockIdx.x * blockDim.x + threadIdx.x;   // 0..2047
  int k = t >> 3, d = t & 7;
  float a = 0.f;
  for (int j = 0; j < HID; ++j)
    a = fmaf(Wo[k * HID + j], Wp[j * 8 + d], a);
  T1[k * 8 + d] = a;
}
__global__ void kc2(const float* __restrict__ Wv, const float* __restrict__ T1,
                    float* __restrict__ T2){
  int t = blockIdx.x * blockDim.x + threadIdx.x;
  int k = t >> 3, d = t & 7;
  float a = 0.f;
  for (int j = 0; j < HID; ++j)
    a = fmaf(Wv[k * HID + j], T1[j * 8 + d], a);
  T2[k * 8 + d] = a;
}
__global__ void kc3(const float* __restrict__ nW2,
                    const float* __restrict__ T2, const float* __restrict__ T1,
                    const float* __restrict__ Wp, const float* __restrict__ bv,
                    const float* __restrict__ bo, const float* __restrict__ bp,
                    const float* __restrict__ nb2,
                    float* __restrict__ Wd, float* __restrict__ bd){
  int t = blockIdx.x * blockDim.x + threadIdx.x;
  int k = t >> 3, d = t & 7;
  float a = 0.f;
  for (int j = 0; j < HID; ++j)
    a = fmaf(nW2[k * HID + j], T2[j * 8 + d], a);
  Wd[k * 8 + d] = a;
  if (t < 8){
    float s = bp[t];
    for (int j = 0; j < HID; ++j){
      s = fmaf(nb2[j], T2[j * 8 + t], s);
      s = fmaf(bv[j],  T1[j * 8 + t], s);
      s = fmaf(bo[j],  Wp[j * 8 + t], s);
    }
    bd[t] = s;
  }
}

// ---------------- K1: batch stats of h' = relu((nf[s]+nf[t])@W1 + 2 b1) ------
__global__ __launch_bounds__(256, 2) void k1_stats(
    const int* __restrict__ eidx, const float* __restrict__ nf,
    const float* __restrict__ W1, const float* __restrict__ b1,
    float* __restrict__ ws_sums, float* __restrict__ ws_sq)
{
  __shared__ unsigned short ctx[4][16 * 40];

  const int tid = threadIdx.x, lane = tid & 63, wid = tid >> 6;
  const int gw = blockIdx.x * 4 + wid, nw = gridDim.x * 4;
  const int m = lane & 15, q = lane >> 4;
  const int r = lane >> 2, side = (lane >> 1) & 1, half = lane & 1;

  short8 w1fr[16];
  build_w1_frags(W1, b1, w1fr, lane);

  unsigned short* myctx = ctx[wid];
  for (int i = lane; i < 16 * 40; i += 64) myctx[i] = 0;
  if (lane < 16) myctx[lane * 40 + 16] = 0x3F80;   // bf16 1.0 at k=16

  f32x4 sacc[16], qacc[16];
  #pragma unroll
  for (int nt = 0; nt < 16; ++nt){
    sacc[nt] = (f32x4){0.f,0.f,0.f,0.f};
    qacc[nt] = (f32x4){0.f,0.f,0.f,0.f};
  }

  int t = gw;
  float4 nfc = make_float4(0.f,0.f,0.f,0.f); int i1 = 0;
  if (t < NTILE){
    int id0 = eidx[side * E_CNT + t * 16 + r];
    nfc = ((const float4*)nf)[id0 * 2 + half];
  }
  { int tn = t + nw;
    if (tn < NTILE) i1 = eidx[side * E_CNT + tn * 16 + r]; }

  for (; t < NTILE; t += nw){
    short4v cv = { (short)f2bf(nfc.x), (short)f2bf(nfc.y),
                   (short)f2bf(nfc.z), (short)f2bf(nfc.w) };
    *(short4v*)&myctx[r * 40 + side * 8 + half * 4] = cv;

    int tn1 = t + nw, tn2 = t + 2 * nw;
    float4 nfn = make_float4(0.f,0.f,0.f,0.f); int i2 = 0;
    if (tn1 < NTILE) nfn = ((const float4*)nf)[i1 * 2 + half];
    if (tn2 < NTILE) i2 = eidx[side * E_CNT + tn2 * 16 + r];

    asm volatile("s_waitcnt lgkmcnt(0)" ::: "memory");
    short8 bfr = *(const short8*)&myctx[m * 40 + q * 8];
    #pragma unroll
    for (int nt = 0; nt < 16; ++nt){
      f32x4 z = {0.f,0.f,0.f,0.f};
      f32x4 c = __builtin_amdgcn_mfma_f32_16x16x32_bf16(w1fr[nt], bfr, z, 0, 0, 0);
      #pragma unroll
      for (int i = 0; i < 4; ++i){
        float h = fminf(fmaxf(c[i], 0.f), 1.0e6f);
        sacc[nt][i] += h;
        qacc[nt][i] = fmaf(h, h, qacc[nt][i]);
      }
    }
    nfc = nfn; i1 = i2;
  }

  #pragma unroll
  for (int nt = 0; nt < 16; ++nt){
    #pragma unroll
    for (int i = 0; i < 4; ++i){
      float v = sacc[nt][i], w = qacc[nt][i];
      v += __shfl_xor(v, 1); w += __shfl_xor(w, 1);
      v += __shfl_xor(v, 2); w += __shfl_xor(w, 2);
      v += __shfl_xor(v, 4); w += __shfl_xor(w, 4);
      v += __shfl_xor(v, 8); w += __shfl_xor(w, 8);
      if (m == 0){
        int j = nt * 16 + q * 4 + i;
        atomicAdd(&ws_sums[j], v);
        atomicAdd(&ws_sq[j], w);
      }
    }
  }
}

// ---------------- K2: fold BN stats into Wd -> Wd2T (bf16) + bd2 -------------
__global__ void k2_fold(const float* __restrict__ gamma,
                        const float* __restrict__ beta,
                        const float* __restrict__ sums, const float* __restrict__ sq,
                        const float* __restrict__ bd, const float* __restrict__ wd,
                        unsigned short* __restrict__ wd2t, float* __restrict__ bd2)
{
  __shared__ float red[256 * 8];
  int j = threadIdx.x;
  const float invE = 1.0f / (float)E_CNT;
  float mu  = sums[j] * invE;                        // stats of h' = 2h
  float var = fmaxf(sq[j] * invE - mu * mu, 0.f);
  float s  = gamma[j] * rsqrtf(var + 4.0f * 1e-5f);  // eps' = 4*eps
  float tt = beta[j] - mu * s;
  #pragma unroll
  for (int d = 0; d < 8; ++d){
    float w = wd[j * 8 + d];
    wd2t[d * HID + j] = f2bf(0.5f * s * w);
    red[j * 8 + d] = tt * w;
  }
  #pragma unroll
  for (int r = 0; r < 8; ++r) wd2t[(8 + r) * HID + j] = 0;   // pad rows d=8..15
  __syncthreads();
  if (j < 8){
    float a = 0.f;
    for (int k = 0; k < 256; ++k) a += red[k * 8 + j];
    bd2[j] = 0.5f * (bd[j] + a);
  }
  if (j >= 8 && j < 16) bd2[j] = 0.f;
}

// ---------------- K3: out = edge_attr + h' @ Wd2 + bd2 ----------------------
__global__ __launch_bounds__(256, 2) void k3_main(
    const int* __restrict__ eidx, const float* __restrict__ nf,
    const float* __restrict__ ea,
    const float* __restrict__ W1, const float* __restrict__ b1,
    const unsigned short* __restrict__ wd2t, const float* __restrict__ bd2,
    float* __restrict__ out)
{
  __shared__ unsigned short ctx[4][16 * 40];
  __shared__ unsigned short hbuf[4][16 * 264];

  const int tid = threadIdx.x, lane = tid & 63, wid = tid >> 6;
  const int gw = blockIdx.x * 4 + wid, ngw = gridDim.x * 4;
  const int m = lane & 15, q = lane >> 4;
  const int r = lane >> 2, side = (lane >> 1) & 1, half = lane & 1;

  short8 w1fr[16];
  build_w1_frags(W1, b1, w1fr, lane);
  short8 w2fr[8];
  #pragma unroll
  for (int kb = 0; kb < 8; ++kb)
    w2fr[kb] = *(const short8*)&wd2t[m * HID + kb * 32 + q * 8];
  const float bd2v = bd2[m];

  unsigned short* myctx = ctx[wid];
  unsigned short* myh   = hbuf[wid];
  for (int i = lane; i < 16 * 40; i += 64) myctx[i] = 0;
  if (lane < 16) myctx[lane * 40 + 16] = 0x3F80;

  int t = gw;
  float4 nfc = make_float4(0.f,0.f,0.f,0.f); int i1 = 0;
  if (t < NTILE){
    int id0 = eidx[side * E_CNT + t * 16 + r];
    nfc = ((const float4*)nf)[id0 * 2 + half];
  }
  { int tn = t + ngw;
    if (tn < NTILE) i1 = eidx[side * E_CNT + tn * 16 + r]; }

  const bool dok = (m < 8);
  for (; t < NTILE; t += ngw){
    short4v cv = { (short)f2bf(nfc.x), (short)f2bf(nfc.y),
                   (short)f2bf(nfc.z), (short)f2bf(nfc.w) };
    *(short4v*)&myctx[r * 40 + side * 8 + half * 4] = cv;

    float eav[4];
    #pragma unroll
    for (int i = 0; i < 4; ++i)
      eav[i] = dok ? ea[(t * 16 + q * 4 + i) * 8 + m] : 0.f;

    int tn1 = t + ngw, tn2 = t + 2 * ngw;
    float4 nfn = make_float4(0.f,0.f,0.f,0.f); int i2 = 0;
    if (tn1 < NTILE) nfn = ((const float4*)nf)[i1 * 2 + half];
    if (tn2 < NTILE) i2 = eidx[side * E_CNT + tn2 * 16 + r];

    asm volatile("s_waitcnt lgkmcnt(0)" ::: "memory");
    short8 bfr = *(const short8*)&myctx[m * 40 + q * 8];
    // mm1: h' tile -> pack bf16 -> LDS (j-contiguous per lane)
    #pragma unroll
    for (int nt = 0; nt < 16; ++nt){
      f32x4 z = {0.f,0.f,0.f,0.f};
      f32x4 c = __builtin_amdgcn_mfma_f32_16x16x32_bf16(w1fr[nt], bfr, z, 0, 0, 0);
      short4v pv = { (short)f2bf(fminf(fmaxf(c[0], 0.f), 1.0e6f)),
                     (short)f2bf(fminf(fmaxf(c[1], 0.f), 1.0e6f)),
                     (short)f2bf(fminf(fmaxf(c[2], 0.f), 1.0e6f)),
                     (short)f2bf(fminf(fmaxf(c[3], 0.f), 1.0e6f)) };
      *(short4v*)&myh[m * 264 + nt * 16 + q * 4] = pv;
    }
    asm volatile("s_waitcnt lgkmcnt(0)" ::: "memory");
    // mm2: out tile = h' @ Wd2
    f32x4 acc = {0.f,0.f,0.f,0.f};
    #pragma unroll
    for (int kb = 0; kb < 8; ++kb){
      short8 afr = *(const short8*)&myh[m * 264 + kb * 32 + q * 8];
      acc = __builtin_amdgcn_mfma_f32_16x16x32_bf16(afr, w2fr[kb], acc, 0, 0, 0);
    }
    if (dok){
      #pragma unroll
      for (int i = 0; i < 4; ++i){
        float o = eav[i] + acc[i] + bd2v;
        out[(t * 16 + q * 4 + i) * 8 + m] = o;
      }
    }
    nfc = nfn; i1 = i2;
  }
}

extern "C" void kernel_launch(void* const* d_in, const int* in_sizes, int n_in,
                              void* d_out, int out_size, void* d_ws, size_t ws_size,
                              hipStream_t stream)
{
  const float* ea   = (const float*)d_in[0];
  const float* nf   = (const float*)d_in[1];
  const int*   eidx = (const int*)d_in[2];
  // d_in[3..8] = edge-encoder params: dead code in the reference.
  const float* nW1    = (const float*)d_in[9];
  const float* nb1    = (const float*)d_in[10];
  const float* ngamma = (const float*)d_in[11];
  const float* nbeta  = (const float*)d_in[12];
  const float* nW2    = (const float*)d_in[13];
  const float* nb2    = (const float*)d_in[14];
  const float* Wv     = (const float*)d_in[15];
  const float* bv     = (const float*)d_in[16];
  const float* Wo     = (const float*)d_in[17];
  const float* bo     = (const float*)d_in[18];
  const float* Wp     = (const float*)d_in[19];
  const float* bp     = (const float*)d_in[20];

  char* ws = (char*)d_ws;
  float* ws_sums          = (float*)(ws + 0);       // 256 f32
  float* ws_sq            = (float*)(ws + 1024);    // 256 f32
  float* ws_bd            = (float*)(ws + 2048);    // 8 f32
  float* ws_bd2           = (float*)(ws + 2112);    // 16 f32
  float* ws_t1            = (float*)(ws + 4096);    // [256][8] f32
  float* ws_t2            = (float*)(ws + 12288);   // [256][8] f32
  float* ws_wd            = (float*)(ws + 20480);   // [256][8] f32
  unsigned short* ws_wd2t = (unsigned short*)(ws + 28672);  // [16][256] bf16

  hipMemsetAsync(ws, 0, 2048, stream);   // zero stats accumulators

  k1_stats<<<dim3(512), dim3(256), 0, stream>>>(
      eidx, nf, nW1, nb1, ws_sums, ws_sq);
  kc1<<<dim3(8), dim3(256), 0, stream>>>(Wo, Wp, ws_t1);
  kc2<<<dim3(8), dim3(256), 0, stream>>>(Wv, ws_t1, ws_t2);
  kc3<<<dim3(8), dim3(256), 0, stream>>>(nW2, ws_t2, ws_t1, Wp, bv, bo, bp, nb2,
                                         ws_wd, ws_bd);
  k2_fold<<<dim3(1), dim3(256), 0, stream>>>(
      ngamma, nbeta, ws_sums, ws_sq, ws_bd, ws_wd, ws_wd2t, ws_bd2);
  k3_main<<<dim3(1024), dim3(256), 0, stream>>>(
      eidx, nf, ea, nW1, nb1, ws_wd2t, ws_bd2, (float*)d_out);
}

// Round 4
// 287.640 us; speedup vs baseline: 1.6946x; 1.6946x over previous
//
#include <hip/hip_runtime.h>

#define E_CNT 500000
#define N_CNT 100000
#define HID   256
#define NTILE 31250   // E/16

typedef short short8 __attribute__((ext_vector_type(8)));
typedef short short4v __attribute__((ext_vector_type(4)));
typedef float f32x4 __attribute__((ext_vector_type(4)));

__device__ __forceinline__ unsigned short f2bf(float f){
  union { float f; unsigned int i; } v; v.f = f;
  unsigned int u = v.i;
  u = u + 0x7FFFu + ((u >> 16) & 1u);
  return (unsigned short)(u >> 16);
}

// Build the 16 A-fragments of W1-augmented (K=32: k0..7=W1, k8..15=W1 again,
// k16=2*b1, rest 0).  mfma_f32_16x16x32_bf16 A layout: m=lane&15, k=(lane>>4)*8+j.
__device__ __forceinline__ void build_w1_frags(const float* W1, const float* b1,
                                               short8* fr, int lane){
  int m = lane & 15, q = lane >> 4;
  #pragma unroll
  for (int nt = 0; nt < 16; ++nt){
    int col = nt * 16 + m;
    short8 a = {0,0,0,0,0,0,0,0};
    if (q < 2){
      #pragma unroll
      for (int j = 0; j < 8; ++j) a[j] = (short)f2bf(W1[j * HID + col]);
    } else if (q == 2){
      a[0] = (short)f2bf(2.0f * b1[col]);
    }
    fr[nt] = a;
  }
}

// ---------------- K1: batch stats of h' = relu((nf[s]+nf[t])@W1 + 2 b1) ------
// No global atomics: per-block deterministic partials -> ws.
__global__ __launch_bounds__(256, 2) void k1_stats(
    const int* __restrict__ eidx, const float* __restrict__ nf,
    const float* __restrict__ W1, const float* __restrict__ b1,
    float* __restrict__ part)
{
  __shared__ unsigned short ctx[4][16 * 40];
  __shared__ float sred[2][4][256];   // 8 KB cross-wave reduce

  const int tid = threadIdx.x, lane = tid & 63, wid = tid >> 6;
  const int gw = blockIdx.x * 4 + wid, nw = gridDim.x * 4;
  const int m = lane & 15, q = lane >> 4;
  const int r = lane >> 2, side = (lane >> 1) & 1, half = lane & 1;

  short8 w1fr[16];
  build_w1_frags(W1, b1, w1fr, lane);

  unsigned short* myctx = ctx[wid];
  for (int i = lane; i < 16 * 40; i += 64) myctx[i] = 0;
  if (lane < 16) myctx[lane * 40 + 16] = 0x3F80;   // bf16 1.0 at k=16

  f32x4 sacc[16], qacc[16];
  #pragma unroll
  for (int nt = 0; nt < 16; ++nt){
    sacc[nt] = (f32x4){0.f,0.f,0.f,0.f};
    qacc[nt] = (f32x4){0.f,0.f,0.f,0.f};
  }

  int t = gw;
  float4 nfc = make_float4(0.f,0.f,0.f,0.f); int i1 = 0;
  if (t < NTILE){
    int id0 = eidx[side * E_CNT + t * 16 + r];
    nfc = ((const float4*)nf)[id0 * 2 + half];
  }
  { int tn = t + nw;
    if (tn < NTILE) i1 = eidx[side * E_CNT + tn * 16 + r]; }

  for (; t < NTILE; t += nw){
    short4v cv = { (short)f2bf(nfc.x), (short)f2bf(nfc.y),
                   (short)f2bf(nfc.z), (short)f2bf(nfc.w) };
    *(short4v*)&myctx[r * 40 + side * 8 + half * 4] = cv;

    int tn1 = t + nw, tn2 = t + 2 * nw;
    float4 nfn = make_float4(0.f,0.f,0.f,0.f); int i2 = 0;
    if (tn1 < NTILE) nfn = ((const float4*)nf)[i1 * 2 + half];
    if (tn2 < NTILE) i2 = eidx[side * E_CNT + tn2 * 16 + r];

    asm volatile("s_waitcnt lgkmcnt(0)" ::: "memory");
    short8 bfr = *(const short8*)&myctx[m * 40 + q * 8];
    #pragma unroll
    for (int nt = 0; nt < 16; ++nt){
      f32x4 z = {0.f,0.f,0.f,0.f};
      f32x4 c = __builtin_amdgcn_mfma_f32_16x16x32_bf16(w1fr[nt], bfr, z, 0, 0, 0);
      #pragma unroll
      for (int i = 0; i < 4; ++i){
        float h = fminf(fmaxf(c[i], 0.f), 1.0e6f);
        sacc[nt][i] += h;
        qacc[nt][i] = fmaf(h, h, qacc[nt][i]);
      }
    }
    nfc = nfn; i1 = i2;
  }

  #pragma unroll
  for (int nt = 0; nt < 16; ++nt){
    #pragma unroll
    for (int i = 0; i < 4; ++i){
      float v = sacc[nt][i], w = qacc[nt][i];
      v += __shfl_xor(v, 1); w += __shfl_xor(w, 1);
      v += __shfl_xor(v, 2); w += __shfl_xor(w, 2);
      v += __shfl_xor(v, 4); w += __shfl_xor(w, 4);
      v += __shfl_xor(v, 8); w += __shfl_xor(w, 8);
      if (m == 0){
        int j = nt * 16 + q * 4 + i;
        sred[0][wid][j] = v;
        sred[1][wid][j] = w;
      }
    }
  }
  __syncthreads();
  {
    int j = tid;
    float s0 = sred[0][0][j] + sred[0][1][j] + sred[0][2][j] + sred[0][3][j];
    float s1 = sred[1][0][j] + sred[1][1][j] + sred[1][2][j] + sred[1][3][j];
    part[blockIdx.x * 512 + j]       = s0;
    part[blockIdx.x * 512 + 256 + j] = s1;
  }
}

// ---------------- KFOLD: reduce partials + weight chain + BN fold -----------
// One block, 256 threads. Thread t owns channel/row t.
__global__ __launch_bounds__(256) void kfold(
    const float* __restrict__ part, int nb,
    const float* __restrict__ gamma, const float* __restrict__ beta,
    const float* __restrict__ Wo, const float* __restrict__ Wp,
    const float* __restrict__ Wv, const float* __restrict__ nW2,
    const float* __restrict__ bv, const float* __restrict__ bo,
    const float* __restrict__ bp, const float* __restrict__ nb2,
    unsigned short* __restrict__ wd2t, float* __restrict__ bd2)
{
  __shared__ float WpL[2048], T1L[2048], T2L[2048], red[2048];
  const int t = threadIdx.x;

  // stats reduce (coalesced: thread t reads part[b*512 + t])
  float s0 = 0.f, s1 = 0.f;
  for (int b = 0; b < nb; ++b){
    s0 += part[b * 512 + t];
    s1 += part[b * 512 + 256 + t];
  }
  const float invE = 1.0f / (float)E_CNT;
  float mu  = s0 * invE;                        // stats of h' = 2h
  float var = fmaxf(s1 * invE - mu * mu, 0.f);
  float s   = gamma[t] * rsqrtf(var + 4.0f * 1e-5f);  // eps' = 4*eps
  float tt  = beta[t] - mu * s;

  for (int i = t; i < 2048; i += 256) WpL[i] = Wp[i];
  __syncthreads();

  float acc[8];
  // T1 row t = Wo[t,:] @ Wp
  #pragma unroll
  for (int d = 0; d < 8; ++d) acc[d] = 0.f;
  for (int jb = 0; jb < 64; ++jb){
    float4 w4 = ((const float4*)(Wo + t * HID))[jb];
    float wv4[4] = {w4.x, w4.y, w4.z, w4.w};
    #pragma unroll
    for (int dj = 0; dj < 4; ++dj){
      int j = jb * 4 + dj;
      #pragma unroll
      for (int d = 0; d < 8; ++d) acc[d] = fmaf(wv4[dj], WpL[j * 8 + d], acc[d]);
    }
  }
  #pragma unroll
  for (int d = 0; d < 8; ++d) T1L[t * 8 + d] = acc[d];
  __syncthreads();

  // T2 row t = Wv[t,:] @ T1
  #pragma unroll
  for (int d = 0; d < 8; ++d) acc[d] = 0.f;
  for (int jb = 0; jb < 64; ++jb){
    float4 w4 = ((const float4*)(Wv + t * HID))[jb];
    float wv4[4] = {w4.x, w4.y, w4.z, w4.w};
    #pragma unroll
    for (int dj = 0; dj < 4; ++dj){
      int j = jb * 4 + dj;
      #pragma unroll
      for (int d = 0; d < 8; ++d) acc[d] = fmaf(wv4[dj], T1L[j * 8 + d], acc[d]);
    }
  }
  #pragma unroll
  for (int d = 0; d < 8; ++d) T2L[t * 8 + d] = acc[d];
  __syncthreads();

  // Wd row t = nW2[t,:] @ T2; fold BN scale/shift
  #pragma unroll
  for (int d = 0; d < 8; ++d) acc[d] = 0.f;
  for (int jb = 0; jb < 64; ++jb){
    float4 w4 = ((const float4*)(nW2 + t * HID))[jb];
    float wv4[4] = {w4.x, w4.y, w4.z, w4.w};
    #pragma unroll
    for (int dj = 0; dj < 4; ++dj){
      int j = jb * 4 + dj;
      #pragma unroll
      for (int d = 0; d < 8; ++d) acc[d] = fmaf(wv4[dj], T2L[j * 8 + d], acc[d]);
    }
  }
  #pragma unroll
  for (int d = 0; d < 8; ++d){
    wd2t[d * HID + t] = f2bf(0.5f * s * acc[d]);
    red[t * 8 + d] = tt * acc[d];
  }
  #pragma unroll
  for (int r = 8; r < 16; ++r) wd2t[r * HID + t] = 0;   // pad rows d=8..15
  __syncthreads();

  if (t < 8){
    float a = bp[t];
    for (int j = 0; j < HID; ++j){
      a = fmaf(nb2[j], T2L[j * 8 + t], a);
      a = fmaf(bv[j],  T1L[j * 8 + t], a);
      a = fmaf(bo[j],  WpL[j * 8 + t], a);
      a += red[j * 8 + t];
    }
    bd2[t] = 0.5f * a;
  }
  if (t >= 8 && t < 16) bd2[t] = 0.f;
}

// ---------------- K3: out = edge_attr + h' @ Wd2 + bd2 ----------------------
__global__ __launch_bounds__(256, 2) void k3_main(
    const int* __restrict__ eidx, const float* __restrict__ nf,
    const float* __restrict__ ea,
    const float* __restrict__ W1, const float* __restrict__ b1,
    const unsigned short* __restrict__ wd2t, const float* __restrict__ bd2,
    float* __restrict__ out)
{
  __shared__ unsigned short ctx[4][16 * 40];
  __shared__ unsigned short hbuf[4][16 * 264];

  const int tid = threadIdx.x, lane = tid & 63, wid = tid >> 6;
  const int gw = blockIdx.x * 4 + wid, ngw = gridDim.x * 4;
  const int m = lane & 15, q = lane >> 4;
  const int r = lane >> 2, side = (lane >> 1) & 1, half = lane & 1;

  short8 w1fr[16];
  build_w1_frags(W1, b1, w1fr, lane);
  short8 w2fr[8];
  #pragma unroll
  for (int kb = 0; kb < 8; ++kb)
    w2fr[kb] = *(const short8*)&wd2t[m * HID + kb * 32 + q * 8];
  const float bd2v = bd2[m];

  unsigned short* myctx = ctx[wid];
  unsigned short* myh   = hbuf[wid];
  for (int i = lane; i < 16 * 40; i += 64) myctx[i] = 0;
  if (lane < 16) myctx[lane * 40 + 16] = 0x3F80;

  int t = gw;
  float4 nfc = make_float4(0.f,0.f,0.f,0.f); int i1 = 0;
  if (t < NTILE){
    int id0 = eidx[side * E_CNT + t * 16 + r];
    nfc = ((const float4*)nf)[id0 * 2 + half];
  }
  { int tn = t + ngw;
    if (tn < NTILE) i1 = eidx[side * E_CNT + tn * 16 + r]; }

  const bool dok = (m < 8);
  for (; t < NTILE; t += ngw){
    short4v cv = { (short)f2bf(nfc.x), (short)f2bf(nfc.y),
                   (short)f2bf(nfc.z), (short)f2bf(nfc.w) };
    *(short4v*)&myctx[r * 40 + side * 8 + half * 4] = cv;

    float eav[4];
    #pragma unroll
    for (int i = 0; i < 4; ++i)
      eav[i] = dok ? ea[(t * 16 + q * 4 + i) * 8 + m] : 0.f;

    int tn1 = t + ngw, tn2 = t + 2 * ngw;
    float4 nfn = make_float4(0.f,0.f,0.f,0.f); int i2 = 0;
    if (tn1 < NTILE) nfn = ((const float4*)nf)[i1 * 2 + half];
    if (tn2 < NTILE) i2 = eidx[side * E_CNT + tn2 * 16 + r];

    asm volatile("s_waitcnt lgkmcnt(0)" ::: "memory");
    short8 bfr = *(const short8*)&myctx[m * 40 + q * 8];
    // mm1: h' tile -> pack bf16 -> LDS (j-contiguous per lane)
    #pragma unroll
    for (int nt = 0; nt < 16; ++nt){
      f32x4 z = {0.f,0.f,0.f,0.f};
      f32x4 c = __builtin_amdgcn_mfma_f32_16x16x32_bf16(w1fr[nt], bfr, z, 0, 0, 0);
      short4v pv = { (short)f2bf(fminf(fmaxf(c[0], 0.f), 1.0e6f)),
                     (short)f2bf(fminf(fmaxf(c[1], 0.f), 1.0e6f)),
                     (short)f2bf(fminf(fmaxf(c[2], 0.f), 1.0e6f)),
                     (short)f2bf(fminf(fmaxf(c[3], 0.f), 1.0e6f)) };
      *(short4v*)&myh[m * 264 + nt * 16 + q * 4] = pv;
    }
    asm volatile("s_waitcnt lgkmcnt(0)" ::: "memory");
    // mm2: out tile = h' @ Wd2
    f32x4 acc = {0.f,0.f,0.f,0.f};
    #pragma unroll
    for (int kb = 0; kb < 8; ++kb){
      short8 afr = *(const short8*)&myh[m * 264 + kb * 32 + q * 8];
      acc = __builtin_amdgcn_mfma_f32_16x16x32_bf16(afr, w2fr[kb], acc, 0, 0, 0);
    }
    if (dok){
      #pragma unroll
      for (int i = 0; i < 4; ++i){
        float o = eav[i] + acc[i] + bd2v;
        out[(t * 16 + q * 4 + i) * 8 + m] = o;
      }
    }
    nfc = nfn; i1 = i2;
  }
}

extern "C" void kernel_launch(void* const* d_in, const int* in_sizes, int n_in,
                              void* d_out, int out_size, void* d_ws, size_t ws_size,
                              hipStream_t stream)
{
  const float* ea   = (const float*)d_in[0];
  const float* nf   = (const float*)d_in[1];
  const int*   eidx = (const int*)d_in[2];
  // d_in[3..8] = edge-encoder params: dead code in the reference.
  const float* nW1    = (const float*)d_in[9];
  const float* nb1    = (const float*)d_in[10];
  const float* ngamma = (const float*)d_in[11];
  const float* nbeta  = (const float*)d_in[12];
  const float* nW2    = (const float*)d_in[13];
  const float* nb2    = (const float*)d_in[14];
  const float* Wv     = (const float*)d_in[15];
  const float* bv     = (const float*)d_in[16];
  const float* Wo     = (const float*)d_in[17];
  const float* bo     = (const float*)d_in[18];
  const float* Wp     = (const float*)d_in[19];
  const float* bp     = (const float*)d_in[20];

  // ws layout: [nb * 512 f32 partials][wd2t 16x256 bf16][bd2 16 f32]
  long avail = (long)ws_size - 8192 - 64 - 256;
  int nb = (int)(avail / 2048);
  if (nb > 256) nb = 256;
  if (nb < 1)   nb = 1;

  char* ws = (char*)d_ws;
  float* ws_part          = (float*)(ws + 0);
  unsigned short* ws_wd2t = (unsigned short*)(ws + (size_t)nb * 2048);
  float* ws_bd2           = (float*)(ws + (size_t)nb * 2048 + 8192);

  k1_stats<<<dim3(nb), dim3(256), 0, stream>>>(eidx, nf, nW1, nb1, ws_part);
  kfold<<<dim3(1), dim3(256), 0, stream>>>(
      ws_part, nb, ngamma, nbeta, Wo, Wp, Wv, nW2, bv, bo, bp, nb2,
      ws_wd2t, ws_bd2);
  k3_main<<<dim3(1024), dim3(256), 0, stream>>>(
      eidx, nf, ea, nW1, nb1, ws_wd2t, ws_bd2, (float*)d_out);
}

// Round 5
// 241.835 us; speedup vs baseline: 2.0156x; 1.1894x over previous
//
#include <hip/hip_runtime.h>

#define E_CNT 500000
#define N_CNT 100000
#define HID   256
#define NTILE 31250   // E/16

typedef short short8 __attribute__((ext_vector_type(8)));
typedef short short4v __attribute__((ext_vector_type(4)));
typedef float f32x4 __attribute__((ext_vector_type(4)));

__device__ __forceinline__ unsigned short f2bf(float f){
  union { float f; unsigned int i; } v; v.f = f;
  unsigned int u = v.i;
  u = u + 0x7FFFu + ((u >> 16) & 1u);
  return (unsigned short)(u >> 16);
}

// Build the 16 A-fragments of W1-augmented (K=32: k0..7=W1, k8..15=W1 again,
// k16=2*b1, rest 0).  mfma_f32_16x16x32_bf16 A layout: m=lane&15, k=(lane>>4)*8+j.
__device__ __forceinline__ void build_w1_frags(const float* W1, const float* b1,
                                               short8* fr, int lane){
  int m = lane & 15, q = lane >> 4;
  #pragma unroll
  for (int nt = 0; nt < 16; ++nt){
    int col = nt * 16 + m;
    short8 a = {0,0,0,0,0,0,0,0};
    if (q < 2){
      #pragma unroll
      for (int j = 0; j < 8; ++j) a[j] = (short)f2bf(W1[j * HID + col]);
    } else if (q == 2){
      a[0] = (short)f2bf(2.0f * b1[col]);
    }
    fr[nt] = a;
  }
}

// ---------------- K1: batch stats of h' = relu((nf[s]+nf[t])@W1 + 2 b1) ------
__global__ __launch_bounds__(256, 2) void k1_stats(
    const int* __restrict__ eidx, const float* __restrict__ nf,
    const float* __restrict__ W1, const float* __restrict__ b1,
    float* __restrict__ part)
{
  __shared__ unsigned short ctx[4][16 * 40];
  __shared__ float sred[2][4][256];

  const int tid = threadIdx.x, lane = tid & 63, wid = tid >> 6;
  const int gw = blockIdx.x * 4 + wid, nw = gridDim.x * 4;
  const int m = lane & 15, q = lane >> 4;
  const int r = lane >> 2, side = (lane >> 1) & 1, half = lane & 1;

  short8 w1fr[16];
  build_w1_frags(W1, b1, w1fr, lane);

  unsigned short* myctx = ctx[wid];
  for (int i = lane; i < 16 * 40; i += 64) myctx[i] = 0;
  if (lane < 16) myctx[lane * 40 + 16] = 0x3F80;   // bf16 1.0 at k=16

  f32x4 sacc[16], qacc[16];
  #pragma unroll
  for (int nt = 0; nt < 16; ++nt){
    sacc[nt] = (f32x4){0.f,0.f,0.f,0.f};
    qacc[nt] = (f32x4){0.f,0.f,0.f,0.f};
  }

  int t = gw;
  float4 nfc = make_float4(0.f,0.f,0.f,0.f); int i1 = 0;
  if (t < NTILE){
    int id0 = eidx[side * E_CNT + t * 16 + r];
    nfc = ((const float4*)nf)[id0 * 2 + half];
  }
  { int tn = t + nw;
    if (tn < NTILE) i1 = eidx[side * E_CNT + tn * 16 + r]; }

  for (; t < NTILE; t += nw){
    short4v cv = { (short)f2bf(nfc.x), (short)f2bf(nfc.y),
                   (short)f2bf(nfc.z), (short)f2bf(nfc.w) };
    *(short4v*)&myctx[r * 40 + side * 8 + half * 4] = cv;

    int tn1 = t + nw, tn2 = t + 2 * nw;
    float4 nfn = make_float4(0.f,0.f,0.f,0.f); int i2 = 0;
    if (tn1 < NTILE) nfn = ((const float4*)nf)[i1 * 2 + half];
    if (tn2 < NTILE) i2 = eidx[side * E_CNT + tn2 * 16 + r];

    asm volatile("s_waitcnt lgkmcnt(0)" ::: "memory");
    short8 bfr = *(const short8*)&myctx[m * 40 + q * 8];
    #pragma unroll
    for (int nt = 0; nt < 16; ++nt){
      f32x4 z = {0.f,0.f,0.f,0.f};
      f32x4 c = __builtin_amdgcn_mfma_f32_16x16x32_bf16(w1fr[nt], bfr, z, 0, 0, 0);
      #pragma unroll
      for (int i = 0; i < 4; ++i){
        float h = fminf(fmaxf(c[i], 0.f), 1.0e6f);
        sacc[nt][i] += h;
        qacc[nt][i] = fmaf(h, h, qacc[nt][i]);
      }
    }
    nfc = nfn; i1 = i2;
  }

  #pragma unroll
  for (int nt = 0; nt < 16; ++nt){
    #pragma unroll
    for (int i = 0; i < 4; ++i){
      float v = sacc[nt][i], w = qacc[nt][i];
      v += __shfl_xor(v, 1); w += __shfl_xor(w, 1);
      v += __shfl_xor(v, 2); w += __shfl_xor(w, 2);
      v += __shfl_xor(v, 4); w += __shfl_xor(w, 4);
      v += __shfl_xor(v, 8); w += __shfl_xor(w, 8);
      if (m == 0){
        int j = nt * 16 + q * 4 + i;
        sred[0][wid][j] = v;
        sred[1][wid][j] = w;
      }
    }
  }
  __syncthreads();
  {
    int j = tid;
    float s0 = sred[0][0][j] + sred[0][1][j] + sred[0][2][j] + sred[0][3][j];
    float s1 = sred[1][0][j] + sred[1][1][j] + sred[1][2][j] + sred[1][3][j];
    part[blockIdx.x * 512 + j]       = s0;
    part[blockIdx.x * 512 + 256 + j] = s1;
  }
}

// ---------------- KCHAIN: 64 blocks, redundant T1/T2, 4 channels of Wd ------
// Block b: full T1 = Wo@Wp and T2 = Wv@T1 in LDS (reads L2-shared across
// blocks), then Wd rows c=4b..4b+3, per-channel stats reduce + BN fold,
// writes wd2t columns, pb[b][8] bias partials. Block 0 exports T1/T2.
__global__ __launch_bounds__(256) void kchain(
    const float* __restrict__ part, int nb,
    const float* __restrict__ gamma, const float* __restrict__ beta,
    const float* __restrict__ Wo, const float* __restrict__ Wp,
    const float* __restrict__ Wv, const float* __restrict__ nW2,
    unsigned short* __restrict__ wd2t, float* __restrict__ pb,
    float* __restrict__ T1s, float* __restrict__ T2s)
{
  __shared__ float WpL[2048], T1L[2048], T2L[2048];
  __shared__ float scr[2048];
  __shared__ float stL[8];
  const int t = threadIdx.x, b = blockIdx.x;

  for (int i = t; i < 2048; i += 256) WpL[i] = Wp[i];

  // stats for this block's 4 channels (c = 4b + cl)
  {
    int cl = t >> 6, i = t & 63;
    int c = b * 4 + cl;
    float s0 = 0.f, s1 = 0.f;
    for (int b2 = i; b2 < nb; b2 += 64){
      s0 += part[b2 * 512 + c];
      s1 += part[b2 * 512 + 256 + c];
    }
    scr[cl * 128 + i]      = s0;
    scr[cl * 128 + 64 + i] = s1;
  }
  __syncthreads();
  if (t < 4){
    float s0 = 0.f, s1 = 0.f;
    for (int i = 0; i < 64; ++i){
      s0 += scr[t * 128 + i];
      s1 += scr[t * 128 + 64 + i];
    }
    const float invE = 1.0f / (float)E_CNT;
    float mu  = s0 * invE;
    float var = fmaxf(s1 * invE - mu * mu, 0.f);
    float s   = gamma[b * 4 + t] * rsqrtf(var + 4.0f * 1e-5f);
    stL[t]     = s;
    stL[4 + t] = beta[b * 4 + t] - mu * s;
  }
  __syncthreads();

  float acc[8];
  // T1 row t = Wo[t,:] @ Wp
  #pragma unroll
  for (int d = 0; d < 8; ++d) acc[d] = 0.f;
  for (int jb = 0; jb < 64; ++jb){
    float4 w4 = ((const float4*)(Wo + t * HID))[jb];
    float wv4[4] = {w4.x, w4.y, w4.z, w4.w};
    #pragma unroll
    for (int dj = 0; dj < 4; ++dj){
      int j = jb * 4 + dj;
      #pragma unroll
      for (int d = 0; d < 8; ++d) acc[d] = fmaf(wv4[dj], WpL[j * 8 + d], acc[d]);
    }
  }
  #pragma unroll
  for (int d = 0; d < 8; ++d) T1L[t * 8 + d] = acc[d];
  __syncthreads();
  if (b == 0) for (int i = t; i < 2048; i += 256) T1s[i] = T1L[i];

  // T2 row t = Wv[t,:] @ T1
  #pragma unroll
  for (int d = 0; d < 8; ++d) acc[d] = 0.f;
  for (int jb = 0; jb < 64; ++jb){
    float4 w4 = ((const float4*)(Wv + t * HID))[jb];
    float wv4[4] = {w4.x, w4.y, w4.z, w4.w};
    #pragma unroll
    for (int dj = 0; dj < 4; ++dj){
      int j = jb * 4 + dj;
      #pragma unroll
      for (int d = 0; d < 8; ++d) acc[d] = fmaf(wv4[dj], T1L[j * 8 + d], acc[d]);
    }
  }
  #pragma unroll
  for (int d = 0; d < 8; ++d) T2L[t * 8 + d] = acc[d];
  __syncthreads();
  if (b == 0) for (int i = t; i < 2048; i += 256) T2s[i] = T2L[i];

  // Wd rows for channels c = 4b + (t>>6); d = (t>>3)&7; p8 = t&7
  {
    int cl = t >> 6, d = (t >> 3) & 7, p8 = t & 7;
    int c = b * 4 + cl;
    const float* row = nW2 + c * HID;
    float a = 0.f;
    for (int j = p8 * 32; j < p8 * 32 + 32; ++j)
      a = fmaf(row[j], T2L[j * 8 + d], a);
    scr[t] = a;
  }
  __syncthreads();
  {
    int cl = t >> 6, d = (t >> 3) & 7, p8 = t & 7;
    if (p8 == 0){
      float w = 0.f;
      #pragma unroll
      for (int i = 0; i < 8; ++i) w += scr[t + i];
      int c = b * 4 + cl;
      wd2t[d * HID + c]       = f2bf(0.5f * stL[cl] * w);
      wd2t[(8 + d) * HID + c] = 0;                 // pad rows d=8..15
      scr[1024 + cl * 8 + d]  = stL[4 + cl] * w;   // tt*Wd contribution
    }
  }
  __syncthreads();
  if (t < 8){
    float a = scr[1024 + t] + scr[1024 + 8 + t] +
              scr[1024 + 16 + t] + scr[1024 + 24 + t];
    pb[b * 8 + t] = a;
  }
}

// ---------------- KD: assemble bd2 (1 block) --------------------------------
__global__ __launch_bounds__(256) void kD(
    const float* __restrict__ pb,
    const float* __restrict__ T1s, const float* __restrict__ T2s,
    const float* __restrict__ Wp,
    const float* __restrict__ bv, const float* __restrict__ bo,
    const float* __restrict__ bp, const float* __restrict__ nb2,
    float* __restrict__ bd2)
{
  __shared__ float red[256];
  const int t = threadIdx.x, d = t & 7, seg = t >> 3;
  float a = 0.f;
  for (int j = seg * 8; j < seg * 8 + 8; ++j){
    a = fmaf(nb2[j], T2s[j * 8 + d], a);
    a = fmaf(bv[j],  T1s[j * 8 + d], a);
    a = fmaf(bo[j],  Wp[j * 8 + d], a);
  }
  for (int b2 = seg; b2 < 64; b2 += 32) a += pb[b2 * 8 + d];
  red[t] = a;
  __syncthreads();
  if (t < 8){
    float s = bp[t];
    for (int sg = 0; sg < 32; ++sg) s += red[sg * 8 + t];
    bd2[t] = 0.5f * s;
  }
  if (t >= 8 && t < 16) bd2[t] = 0.f;
}

// ---------------- K3: out = edge_attr + h' @ Wd2 + bd2 ----------------------
__global__ __launch_bounds__(256, 2) void k3_main(
    const int* __restrict__ eidx, const float* __restrict__ nf,
    const float* __restrict__ ea,
    const float* __restrict__ W1, const float* __restrict__ b1,
    const unsigned short* __restrict__ wd2t, const float* __restrict__ bd2,
    float* __restrict__ out)
{
  __shared__ unsigned short ctx[4][16 * 40];
  __shared__ unsigned short hbuf[4][16 * 264];

  const int tid = threadIdx.x, lane = tid & 63, wid = tid >> 6;
  const int gw = blockIdx.x * 4 + wid, ngw = gridDim.x * 4;
  const int m = lane & 15, q = lane >> 4;
  const int r = lane >> 2, side = (lane >> 1) & 1, half = lane & 1;

  short8 w1fr[16];
  build_w1_frags(W1, b1, w1fr, lane);
  short8 w2fr[8];
  #pragma unroll
  for (int kb = 0; kb < 8; ++kb)
    w2fr[kb] = *(const short8*)&wd2t[m * HID + kb * 32 + q * 8];
  const float bd2v = bd2[m];

  unsigned short* myctx = ctx[wid];
  unsigned short* myh   = hbuf[wid];
  for (int i = lane; i < 16 * 40; i += 64) myctx[i] = 0;
  if (lane < 16) myctx[lane * 40 + 16] = 0x3F80;

  int t = gw;
  float4 nfc = make_float4(0.f,0.f,0.f,0.f); int i1 = 0;
  if (t < NTILE){
    int id0 = eidx[side * E_CNT + t * 16 + r];
    nfc = ((const float4*)nf)[id0 * 2 + half];
  }
  { int tn = t + ngw;
    if (tn < NTILE) i1 = eidx[side * E_CNT + tn * 16 + r]; }

  const bool dok = (m < 8);
  for (; t < NTILE; t += ngw){
    short4v cv = { (short)f2bf(nfc.x), (short)f2bf(nfc.y),
                   (short)f2bf(nfc.z), (short)f2bf(nfc.w) };
    *(short4v*)&myctx[r * 40 + side * 8 + half * 4] = cv;

    float eav[4];
    #pragma unroll
    for (int i = 0; i < 4; ++i)
      eav[i] = dok ? ea[(t * 16 + q * 4 + i) * 8 + m] : 0.f;

    int tn1 = t + ngw, tn2 = t + 2 * ngw;
    float4 nfn = make_float4(0.f,0.f,0.f,0.f); int i2 = 0;
    if (tn1 < NTILE) nfn = ((const float4*)nf)[i1 * 2 + half];
    if (tn2 < NTILE) i2 = eidx[side * E_CNT + tn2 * 16 + r];

    asm volatile("s_waitcnt lgkmcnt(0)" ::: "memory");
    short8 bfr = *(const short8*)&myctx[m * 40 + q * 8];
    // mm1: h' tile -> pack bf16 -> LDS (j-contiguous per lane)
    #pragma unroll
    for (int nt = 0; nt < 16; ++nt){
      f32x4 z = {0.f,0.f,0.f,0.f};
      f32x4 c = __builtin_amdgcn_mfma_f32_16x16x32_bf16(w1fr[nt], bfr, z, 0, 0, 0);
      short4v pv = { (short)f2bf(fminf(fmaxf(c[0], 0.f), 1.0e6f)),
                     (short)f2bf(fminf(fmaxf(c[1], 0.f), 1.0e6f)),
                     (short)f2bf(fminf(fmaxf(c[2], 0.f), 1.0e6f)),
                     (short)f2bf(fminf(fmaxf(c[3], 0.f), 1.0e6f)) };
      *(short4v*)&myh[m * 264 + nt * 16 + q * 4] = pv;
    }
    asm volatile("s_waitcnt lgkmcnt(0)" ::: "memory");
    // mm2: out tile = h' @ Wd2
    f32x4 acc = {0.f,0.f,0.f,0.f};
    #pragma unroll
    for (int kb = 0; kb < 8; ++kb){
      short8 afr = *(const short8*)&myh[m * 264 + kb * 32 + q * 8];
      acc = __builtin_amdgcn_mfma_f32_16x16x32_bf16(afr, w2fr[kb], acc, 0, 0, 0);
    }
    if (dok){
      #pragma unroll
      for (int i = 0; i < 4; ++i){
        float o = eav[i] + acc[i] + bd2v;
        out[(t * 16 + q * 4 + i) * 8 + m] = o;
      }
    }
    nfc = nfn; i1 = i2;
  }
}

extern "C" void kernel_launch(void* const* d_in, const int* in_sizes, int n_in,
                              void* d_out, int out_size, void* d_ws, size_t ws_size,
                              hipStream_t stream)
{
  const float* ea   = (const float*)d_in[0];
  const float* nf   = (const float*)d_in[1];
  const int*   eidx = (const int*)d_in[2];
  const float* nW1    = (const float*)d_in[9];
  const float* nb1    = (const float*)d_in[10];
  const float* ngamma = (const float*)d_in[11];
  const float* nbeta  = (const float*)d_in[12];
  const float* nW2    = (const float*)d_in[13];
  const float* nb2    = (const float*)d_in[14];
  const float* Wv     = (const float*)d_in[15];
  const float* bv     = (const float*)d_in[16];
  const float* Wo     = (const float*)d_in[17];
  const float* bo     = (const float*)d_in[18];
  const float* Wp     = (const float*)d_in[19];
  const float* bp     = (const float*)d_in[20];

  // ws layout: [nb*512 f32 part][wd2t 16x256 bf16][bd2 16 f32][T1s][T2s][pb]
  long avail = (long)ws_size - 32768;
  int nb = (int)(avail / 2048);
  if (nb > 1024) nb = 1024;
  if (nb < 1)    nb = 1;

  char* ws = (char*)d_ws;
  size_t off = (size_t)nb * 2048;
  float* ws_part          = (float*)(ws + 0);
  unsigned short* ws_wd2t = (unsigned short*)(ws + off);
  float* ws_bd2           = (float*)(ws + off + 8192);
  float* ws_t1            = (float*)(ws + off + 8192 + 64);
  float* ws_t2            = (float*)(ws + off + 8192 + 64 + 8192);
  float* ws_pb            = (float*)(ws + off + 8192 + 64 + 16384);

  k1_stats<<<dim3(nb), dim3(256), 0, stream>>>(eidx, nf, nW1, nb1, ws_part);
  kchain<<<dim3(64), dim3(256), 0, stream>>>(
      ws_part, nb, ngamma, nbeta, Wo, Wp, Wv, nW2,
      ws_wd2t, ws_pb, ws_t1, ws_t2);
  kD<<<dim3(1), dim3(256), 0, stream>>>(
      ws_pb, ws_t1, ws_t2, Wp, bv, bo, bp, nb2, ws_bd2);
  k3_main<<<dim3(2048), dim3(256), 0, stream>>>(
      eidx, nf, ea, nW1, nb1, ws_wd2t, ws_bd2, (float*)d_out);
}

// Round 6
// 218.419 us; speedup vs baseline: 2.2317x; 1.1072x over previous
//
#include <hip/hip_runtime.h>
#include <hip/hip_bf16.h>
#include <string.h>

#define E_CNT 500000
#define N_CNT 100000
#define HID   256
#define NTILE 31250   // E/16

typedef short short8 __attribute__((ext_vector_type(8)));
typedef float f32x4 __attribute__((ext_vector_type(4)));

__device__ __forceinline__ unsigned short f2bf(float f){
  union { float f; unsigned int i; } v; v.f = f;
  unsigned int u = v.i;
  u = u + 0x7FFFu + ((u >> 16) & 1u);
  return (unsigned short)(u >> 16);
}

__device__ __forceinline__ unsigned int pk_bf16(float a, float b){
  __hip_bfloat162 p = __float22bfloat162_rn(make_float2(a, b));
  unsigned int u; memcpy(&u, &p, 4); return u;
}

// Shared-LDS W1-augmented A-fragments: row ch (48 B stride, 24 shorts):
// k0..7 = W1[k][ch], k8..15 = W1[k-8][ch], k16 = 2*b1[ch], k17..23 = 0.
// Frag for (nt, lane): ds_read_b128 at shorts (nt*16+m)*24 + q*8.
// q=3 reads spill into next row: multiplied by B rows 24..31 == 0, harmless.
__device__ __forceinline__ void init_w1_lds(unsigned short* w1l,
                                            const float* W1, const float* b1,
                                            int tid){
  int ch = tid;
  #pragma unroll
  for (int j = 0; j < 8; ++j){
    unsigned short w = f2bf(W1[j * HID + ch]);
    w1l[ch * 24 + j]     = w;
    w1l[ch * 24 + 8 + j] = w;
  }
  w1l[ch * 24 + 16] = f2bf(2.0f * b1[ch]);
  #pragma unroll
  for (int j = 17; j < 24; ++j) w1l[ch * 24 + j] = 0;
  if (tid < 32) w1l[256 * 24 + tid] = 0;   // tail pad for q=3 of ch=255
}

// ---------------- K1: batch stats of h' = relu((nf[s]+nf[t])@W1 + 2 b1) ------
__global__ __launch_bounds__(256, 3) void k1_stats(
    const int* __restrict__ eidx, const float* __restrict__ nf,
    const float* __restrict__ W1, const float* __restrict__ b1,
    float* __restrict__ part, float* __restrict__ bd2)
{
  __shared__ unsigned short w1l[256 * 24 + 32];
  __shared__ unsigned short ctx[4][16 * 40];
  __shared__ float sred[2][4][256];

  const int tid = threadIdx.x, lane = tid & 63, wid = tid >> 6;
  const int gw = blockIdx.x * 4 + wid, nw = gridDim.x * 4;
  const int m = lane & 15, q = lane >> 4;
  const int r = lane >> 2, side = (lane >> 1) & 1, half = lane & 1;

  if (blockIdx.x == 0 && tid < 16) bd2[tid] = 0.f;   // kchain atomicAdds later

  init_w1_lds(w1l, W1, b1, tid);

  unsigned short* myctx = ctx[wid];
  for (int i = lane; i < 16 * 40; i += 64) myctx[i] = 0;
  if (lane < 16) myctx[lane * 40 + 16] = 0x3F80;   // bf16 1.0 at k=16
  __syncthreads();

  const f32x4 z4 = {0.f, 0.f, 0.f, 0.f};
  f32x4 sacc[16], qacc[16];
  #pragma unroll
  for (int nt = 0; nt < 16; ++nt){ sacc[nt] = z4; qacc[nt] = z4; }

  int t = gw;
  float4 nfc = make_float4(0.f,0.f,0.f,0.f); int i1 = 0;
  if (t < NTILE){
    int id0 = eidx[side * E_CNT + t * 16 + r];
    nfc = ((const float4*)nf)[id0 * 2 + half];
  }
  { int tn = t + nw;
    if (tn < NTILE) i1 = eidx[side * E_CNT + tn * 16 + r]; }

  for (; t < NTILE; t += nw){
    *(uint2*)&myctx[r * 40 + side * 8 + half * 4] =
        make_uint2(pk_bf16(nfc.x, nfc.y), pk_bf16(nfc.z, nfc.w));

    int tn1 = t + nw, tn2 = t + 2 * nw;
    float4 nfn = make_float4(0.f,0.f,0.f,0.f); int i2 = 0;
    if (tn1 < NTILE) nfn = ((const float4*)nf)[i1 * 2 + half];
    if (tn2 < NTILE) i2 = eidx[side * E_CNT + tn2 * 16 + r];

    asm volatile("s_waitcnt lgkmcnt(0)" ::: "memory");
    short8 bfr = *(const short8*)&myctx[m * 40 + q * 8];
    #pragma unroll
    for (int nt = 0; nt < 16; ++nt){
      short8 afr = *(const short8*)&w1l[(nt * 16 + m) * 24 + q * 8];
      f32x4 c = __builtin_amdgcn_mfma_f32_16x16x32_bf16(afr, bfr, z4, 0, 0, 0);
      f32x4 hv = __builtin_elementwise_max(c, z4);
      sacc[nt] += hv;
      qacc[nt] += hv * hv;
    }
    nfc = nfn; i1 = i2;
  }

  #pragma unroll
  for (int nt = 0; nt < 16; ++nt){
    #pragma unroll
    for (int i = 0; i < 4; ++i){
      float v = sacc[nt][i], w = qacc[nt][i];
      v += __shfl_xor(v, 1); w += __shfl_xor(w, 1);
      v += __shfl_xor(v, 2); w += __shfl_xor(w, 2);
      v += __shfl_xor(v, 4); w += __shfl_xor(w, 4);
      v += __shfl_xor(v, 8); w += __shfl_xor(w, 8);
      if (m == 0){
        int j = nt * 16 + q * 4 + i;
        sred[0][wid][j] = v;
        sred[1][wid][j] = w;
      }
    }
  }
  __syncthreads();
  {
    int j = tid;
    float s0 = sred[0][0][j] + sred[0][1][j] + sred[0][2][j] + sred[0][3][j];
    float s1 = sred[1][0][j] + sred[1][1][j] + sred[1][2][j] + sred[1][3][j];
    part[blockIdx.x * 512 + j]       = s0;
    part[blockIdx.x * 512 + 256 + j] = s1;
  }
}

// ---------------- KCHAIN: 64 blocks, redundant T1/T2, 4 channels of Wd ------
// + folded bias assembly: every block atomicAdds its tt*Wd term into bd2;
// block 0 also adds the static chain (nb2@T2 + bv@T1 + bo@Wp + bp).
__global__ __launch_bounds__(256) void kchain(
    const float* __restrict__ part, int nb,
    const float* __restrict__ gamma, const float* __restrict__ beta,
    const float* __restrict__ Wo, const float* __restrict__ Wp,
    const float* __restrict__ Wv, const float* __restrict__ nW2,
    const float* __restrict__ bv, const float* __restrict__ bo,
    const float* __restrict__ bp, const float* __restrict__ nb2,
    unsigned short* __restrict__ wd2t, float* __restrict__ bd2)
{
  __shared__ float WpL[2048], T1L[2048], T2L[2048];
  __shared__ float scr[2048];
  __shared__ float stL[8];
  const int t = threadIdx.x, b = blockIdx.x;

  for (int i = t; i < 2048; i += 256) WpL[i] = Wp[i];

  {
    int cl = t >> 6, i = t & 63;
    int c = b * 4 + cl;
    float s0 = 0.f, s1 = 0.f;
    for (int b2 = i; b2 < nb; b2 += 64){
      s0 += part[b2 * 512 + c];
      s1 += part[b2 * 512 + 256 + c];
    }
    scr[cl * 128 + i]      = s0;
    scr[cl * 128 + 64 + i] = s1;
  }
  __syncthreads();
  if (t < 4){
    float s0 = 0.f, s1 = 0.f;
    for (int i = 0; i < 64; ++i){
      s0 += scr[t * 128 + i];
      s1 += scr[t * 128 + 64 + i];
    }
    const float invE = 1.0f / (float)E_CNT;
    float mu  = s0 * invE;
    float var = fmaxf(s1 * invE - mu * mu, 0.f);
    float s   = gamma[b * 4 + t] * rsqrtf(var + 4.0f * 1e-5f);  // eps' = 4*eps
    stL[t]     = s;
    stL[4 + t] = beta[b * 4 + t] - mu * s;
  }
  __syncthreads();

  float acc[8];
  #pragma unroll
  for (int d = 0; d < 8; ++d) acc[d] = 0.f;
  for (int jb = 0; jb < 64; ++jb){
    float4 w4 = ((const float4*)(Wo + t * HID))[jb];
    float wv4[4] = {w4.x, w4.y, w4.z, w4.w};
    #pragma unroll
    for (int dj = 0; dj < 4; ++dj){
      int j = jb * 4 + dj;
      #pragma unroll
      for (int d = 0; d < 8; ++d) acc[d] = fmaf(wv4[dj], WpL[j * 8 + d], acc[d]);
    }
  }
  #pragma unroll
  for (int d = 0; d < 8; ++d) T1L[t * 8 + d] = acc[d];
  __syncthreads();

  #pragma unroll
  for (int d = 0; d < 8; ++d) acc[d] = 0.f;
  for (int jb = 0; jb < 64; ++jb){
    float4 w4 = ((const float4*)(Wv + t * HID))[jb];
    float wv4[4] = {w4.x, w4.y, w4.z, w4.w};
    #pragma unroll
    for (int dj = 0; dj < 4; ++dj){
      int j = jb * 4 + dj;
      #pragma unroll
      for (int d = 0; d < 8; ++d) acc[d] = fmaf(wv4[dj], T1L[j * 8 + d], acc[d]);
    }
  }
  #pragma unroll
  for (int d = 0; d < 8; ++d) T2L[t * 8 + d] = acc[d];
  __syncthreads();

  {
    int cl = t >> 6, d = (t >> 3) & 7, p8 = t & 7;
    int c = b * 4 + cl;
    const float* row = nW2 + c * HID;
    float a = 0.f;
    for (int j = p8 * 32; j < p8 * 32 + 32; ++j)
      a = fmaf(row[j], T2L[j * 8 + d], a);
    scr[t] = a;
  }
  __syncthreads();
  {
    int cl = t >> 6, d = (t >> 3) & 7, p8 = t & 7;
    if (p8 == 0){
      float w = 0.f;
      #pragma unroll
      for (int i = 0; i < 8; ++i) w += scr[t + i];
      int c = b * 4 + cl;
      wd2t[d * HID + c]       = f2bf(0.5f * stL[cl] * w);
      wd2t[(8 + d) * HID + c] = 0;                 // pad rows d=8..15
      scr[1024 + cl * 8 + d]  = stL[4 + cl] * w;   // tt*Wd contribution
    }
  }
  __syncthreads();
  if (t < 8){
    float a = scr[1024 + t] + scr[1024 + 8 + t] +
              scr[1024 + 16 + t] + scr[1024 + 24 + t];
    if (b == 0){
      float s2 = bp[t];
      for (int j = 0; j < HID; ++j){
        s2 = fmaf(nb2[j], T2L[j * 8 + t], s2);
        s2 = fmaf(bv[j],  T1L[j * 8 + t], s2);
        s2 = fmaf(bo[j],  WpL[j * 8 + t], s2);
      }
      a += s2;
    }
    atomicAdd(&bd2[t], a);
  }
}

// ---------------- K3: out = edge_attr + h' @ Wd2 + bd2 ----------------------
__global__ __launch_bounds__(256, 3) void k3_main(
    const int* __restrict__ eidx, const float* __restrict__ nf,
    const float* __restrict__ ea,
    const float* __restrict__ W1, const float* __restrict__ b1,
    const unsigned short* __restrict__ wd2t, const float* __restrict__ bd2,
    float* __restrict__ out)
{
  __shared__ unsigned short w1l[256 * 24 + 32];
  __shared__ unsigned short ctx[4][16 * 40];
  __shared__ unsigned short hbuf[4][16 * 264];

  const int tid = threadIdx.x, lane = tid & 63, wid = tid >> 6;
  const int gw = blockIdx.x * 4 + wid, ngw = gridDim.x * 4;
  const int m = lane & 15, q = lane >> 4;
  const int r = lane >> 2, side = (lane >> 1) & 1, half = lane & 1;

  init_w1_lds(w1l, W1, b1, tid);

  short8 w2fr[8];
  #pragma unroll
  for (int kb = 0; kb < 8; ++kb)
    w2fr[kb] = *(const short8*)&wd2t[m * HID + kb * 32 + q * 8];
  const float bd2v = (m < 8) ? 0.5f * bd2[m] : 0.f;

  unsigned short* myctx = ctx[wid];
  unsigned short* myh   = hbuf[wid];
  for (int i = lane; i < 16 * 40; i += 64) myctx[i] = 0;
  if (lane < 16) myctx[lane * 40 + 16] = 0x3F80;
  __syncthreads();

  const f32x4 z4 = {0.f, 0.f, 0.f, 0.f};

  int t = gw;
  float4 nfc = make_float4(0.f,0.f,0.f,0.f); int i1 = 0;
  if (t < NTILE){
    int id0 = eidx[side * E_CNT + t * 16 + r];
    nfc = ((const float4*)nf)[id0 * 2 + half];
  }
  { int tn = t + ngw;
    if (tn < NTILE) i1 = eidx[side * E_CNT + tn * 16 + r]; }

  const bool dok = (m < 8);
  for (; t < NTILE; t += ngw){
    *(uint2*)&myctx[r * 40 + side * 8 + half * 4] =
        make_uint2(pk_bf16(nfc.x, nfc.y), pk_bf16(nfc.z, nfc.w));

    float eav[4];
    #pragma unroll
    for (int i = 0; i < 4; ++i)
      eav[i] = dok ? ea[(t * 16 + q * 4 + i) * 8 + m] : 0.f;

    int tn1 = t + ngw, tn2 = t + 2 * ngw;
    float4 nfn = make_float4(0.f,0.f,0.f,0.f); int i2 = 0;
    if (tn1 < NTILE) nfn = ((const float4*)nf)[i1 * 2 + half];
    if (tn2 < NTILE) i2 = eidx[side * E_CNT + tn2 * 16 + r];

    asm volatile("s_waitcnt lgkmcnt(0)" ::: "memory");
    short8 bfr = *(const short8*)&myctx[m * 40 + q * 8];
    // mm1: h' tile -> packed bf16 -> LDS (j-contiguous per lane)
    #pragma unroll
    for (int nt = 0; nt < 16; ++nt){
      short8 afr = *(const short8*)&w1l[(nt * 16 + m) * 24 + q * 8];
      f32x4 c = __builtin_amdgcn_mfma_f32_16x16x32_bf16(afr, bfr, z4, 0, 0, 0);
      f32x4 hv = __builtin_elementwise_max(c, z4);
      *(uint2*)&myh[m * 264 + nt * 16 + q * 4] =
          make_uint2(pk_bf16(hv[0], hv[1]), pk_bf16(hv[2], hv[3]));
    }
    asm volatile("s_waitcnt lgkmcnt(0)" ::: "memory");
    // mm2: out tile = h' @ Wd2
    f32x4 acc = z4;
    #pragma unroll
    for (int kb = 0; kb < 8; ++kb){
      short8 afr = *(const short8*)&myh[m * 264 + kb * 32 + q * 8];
      acc = __builtin_amdgcn_mfma_f32_16x16x32_bf16(afr, w2fr[kb], acc, 0, 0, 0);
    }
    if (dok){
      #pragma unroll
      for (int i = 0; i < 4; ++i){
        float o = eav[i] + acc[i] + bd2v;
        out[(t * 16 + q * 4 + i) * 8 + m] = o;
      }
    }
    nfc = nfn; i1 = i2;
  }
}

extern "C" void kernel_launch(void* const* d_in, const int* in_sizes, int n_in,
                              void* d_out, int out_size, void* d_ws, size_t ws_size,
                              hipStream_t stream)
{
  const float* ea   = (const float*)d_in[0];
  const float* nf   = (const float*)d_in[1];
  const int*   eidx = (const int*)d_in[2];
  // d_in[3..8] = edge-encoder params: dead code in the reference.
  const float* nW1    = (const float*)d_in[9];
  const float* nb1    = (const float*)d_in[10];
  const float* ngamma = (const float*)d_in[11];
  const float* nbeta  = (const float*)d_in[12];
  const float* nW2    = (const float*)d_in[13];
  const float* nb2    = (const float*)d_in[14];
  const float* Wv     = (const float*)d_in[15];
  const float* bv     = (const float*)d_in[16];
  const float* Wo     = (const float*)d_in[17];
  const float* bo     = (const float*)d_in[18];
  const float* Wp     = (const float*)d_in[19];
  const float* bp     = (const float*)d_in[20];

  // ws layout: [nb*512 f32 part][wd2t 16x256 bf16][bd2 16 f32]
  long avail = (long)ws_size - 8192 - 64;
  int nb = (int)(avail / 2048);
  if (nb > 768) nb = 768;
  if (nb < 1)   nb = 1;

  char* ws = (char*)d_ws;
  float* ws_part          = (float*)(ws + 0);
  unsigned short* ws_wd2t = (unsigned short*)(ws + (size_t)nb * 2048);
  float* ws_bd2           = (float*)(ws + (size_t)nb * 2048 + 8192);

  k1_stats<<<dim3(nb), dim3(256), 0, stream>>>(eidx, nf, nW1, nb1,
                                               ws_part, ws_bd2);
  kchain<<<dim3(64), dim3(256), 0, stream>>>(
      ws_part, nb, ngamma, nbeta, Wo, Wp, Wv, nW2, bv, bo, bp, nb2,
      ws_wd2t, ws_bd2);
  k3_main<<<dim3(768), dim3(256), 0, stream>>>(
      eidx, nf, ea, nW1, nb1, ws_wd2t, ws_bd2, (float*)d_out);
}